// Round 6
// baseline (316.987 us; speedup 1.0000x reference)
//
#include <hip/hip_runtime.h>

typedef __bf16 bf16;
typedef __bf16 bf16x4 __attribute__((ext_vector_type(4)));
typedef __bf16 bf16x8 __attribute__((ext_vector_type(8)));
typedef float f32x4 __attribute__((ext_vector_type(4)));

#define S_LEN 2048
#define HIDDEN 2048
#define NH 16
#define NKV 8
#define HD 128
#define QKV_N 4096

// partial slot: 128x128 f32 O (65536 B) + 128x{m,l} f32 (1024 B)
#define PSLOT 66560

__device__ __forceinline__ void async_load16(const void* g, void* l) {
  __builtin_amdgcn_global_load_lds((const __attribute__((address_space(1))) unsigned int*)g,
                                   (__attribute__((address_space(3))) unsigned int*)l,
                                   16, 0, 0);
}

// ---- DPP 16-lane (row) reductions: row == our quad domain (l15) ----
template <int C>
__device__ __forceinline__ float dpp_f(float x) {
  return __builtin_bit_cast(float, __builtin_amdgcn_mov_dpp(
      __builtin_bit_cast(int, x), C, 0xF, 0xF, true));
}
__device__ __forceinline__ float rowmax16(float x) {
  x = fmaxf(x, dpp_f<0x128>(x));  // row_ror:8
  x = fmaxf(x, dpp_f<0x124>(x));  // row_ror:4
  x = fmaxf(x, dpp_f<0x122>(x));  // row_ror:2
  x = fmaxf(x, dpp_f<0x121>(x));  // row_ror:1
  return x;
}
__device__ __forceinline__ float rowsum16(float x) {
  x += dpp_f<0x128>(x);
  x += dpp_f<0x124>(x);
  x += dpp_f<0x122>(x);
  x += dpp_f<0x121>(x);
  return x;
}

// ---------------- fp32 -> bf16 convert (single) ----------------
__global__ __launch_bounds__(256)
void cvt_f32_bf16(const float* __restrict__ src, bf16* __restrict__ dst, int n) {
  int i = (blockIdx.x * 256 + threadIdx.x) * 4;
  if (i < n) {
    float4 v = *(const float4*)(src + i);
    bf16x4 o = {(bf16)v.x, (bf16)v.y, (bf16)v.z, (bf16)v.w};
    *(bf16x4*)(dst + i) = o;
  }
}

// ---------------- fp32 -> bf16 convert (two arrays fused) ----------------
__global__ __launch_bounds__(256)
void cvt_pair(const float* __restrict__ s1, bf16* __restrict__ d1, int n1,
              const float* __restrict__ s2, bf16* __restrict__ d2, int n2) {
  int i = (blockIdx.x * 256 + threadIdx.x) * 4;
  const float* s;
  bf16* d;
  int j;
  if (i < n1) { s = s1; d = d1; j = i; }
  else        { s = s2; d = d2; j = i - n1; if (j >= n2) return; }
  float4 v = *(const float4*)(s + j);
  bf16x4 o = {(bf16)v.x, (bf16)v.y, (bf16)v.z, (bf16)v.w};
  *(bf16x4*)(d + j) = o;
}

// ---------------- GEMM 128x128: C[M,N] = A[M,K] * B[N,K]^T + bias ----------------
// Double-buffered LDS 2-phase + XCD column-chunk swizzle: each XCD owns gx/8
// contiguous n-columns (m fastest within XCD) so B-panels are XCD-L2-resident.
// Requires gridDim.x % 8 == 0 (true for both launches).
template <int WRITE_BF16>
__global__ __launch_bounds__(256)
void gemm_bt(const bf16* __restrict__ A, const bf16* __restrict__ B,
             const float* __restrict__ bias, void* __restrict__ Cout,
             int M, int N, int K) {
  __shared__ bf16 As[2][128 * 32];
  __shared__ bf16 Bs[2][128 * 32];
  const int tid = threadIdx.x;
  const int w = tid >> 6, lane = tid & 63;
  const int quad = lane >> 4, l15 = lane & 15;
  const int wm = w >> 1, wn = w & 1;

  // XCD-aware remap of flat block id
  const int flat = blockIdx.y * gridDim.x + blockIdx.x;
  const int xcd = flat & 7, loc = flat >> 3;
  const int colsPer = gridDim.x >> 3;
  const int nidx = xcd * colsPer + loc / gridDim.y;
  const int midx = loc % gridDim.y;
  const int m0 = midx * 128, n0 = nidx * 128;

  f32x4 acc[4][4];
#pragma unroll
  for (int i = 0; i < 4; i++)
#pragma unroll
    for (int j = 0; j < 4; j++) acc[i][j] = (f32x4){0.f, 0.f, 0.f, 0.f};

  const int crow = lane >> 2;
  const int ccol = (lane & 3) * 8;

  // prologue: stage k0=0 into buf 0
#pragma unroll
  for (int q = 0; q < 2; q++) {
    int c = 2 * w + q;
    async_load16(A + (size_t)(m0 + c * 16 + crow) * K + ccol, (char*)As[0] + c * 1024);
    async_load16(B + (size_t)(n0 + c * 16 + crow) * K + ccol, (char*)Bs[0] + c * 1024);
  }

  int cur = 0;
  for (int k0 = 0; k0 < K; k0 += 32) {
    __asm__ __volatile__("s_waitcnt vmcnt(0)" ::: "memory");  // buf[cur] DMA landed
    __syncthreads();
    if (k0 + 32 < K) {
#pragma unroll
      for (int q = 0; q < 2; q++) {
        int c = 2 * w + q;
        async_load16(A + (size_t)(m0 + c * 16 + crow) * K + k0 + 32 + ccol,
                     (char*)As[cur ^ 1] + c * 1024);
        async_load16(B + (size_t)(n0 + c * 16 + crow) * K + k0 + 32 + ccol,
                     (char*)Bs[cur ^ 1] + c * 1024);
      }
    }
    bf16x8 af[4], bfr[4];
#pragma unroll
    for (int i = 0; i < 4; i++)
      af[i] = *(const bf16x8*)(As[cur] + (wm * 64 + i * 16 + l15) * 32 + quad * 8);
#pragma unroll
    for (int j = 0; j < 4; j++)
      bfr[j] = *(const bf16x8*)(Bs[cur] + (wn * 64 + j * 16 + l15) * 32 + quad * 8);
#pragma unroll
    for (int i = 0; i < 4; i++)
#pragma unroll
      for (int j = 0; j < 4; j++)
        acc[i][j] = __builtin_amdgcn_mfma_f32_16x16x32_bf16(af[i], bfr[j], acc[i][j], 0, 0, 0);
    cur ^= 1;
  }

#pragma unroll
  for (int i = 0; i < 4; i++) {
#pragma unroll
    for (int j = 0; j < 4; j++) {
      int col = n0 + wn * 64 + j * 16 + l15;
      float bv = bias[col];
#pragma unroll
      for (int r = 0; r < 4; r++) {
        int row = m0 + wm * 64 + i * 16 + quad * 4 + r;
        float v = acc[i][j][r] + bv;
        if (WRITE_BF16)
          ((bf16*)Cout)[(size_t)row * N + col] = (bf16)v;
        else
          ((float*)Cout)[(size_t)row * N + col] = v;
      }
    }
  }
}

// ---------------- RMS norm + RoPE -> Q/K head-major bf16 ----------------
// Q is pre-scaled by D^-0.5 * log2(e) so attn softmax uses raw QK^T logits in base-2.
__global__ __launch_bounds__(128)
void normrope(const bf16* __restrict__ qkv, const int* __restrict__ idx,
              const float* __restrict__ qnw, const float* __restrict__ knw,
              const float* __restrict__ qnhw, const float* __restrict__ knhw,
              bf16* __restrict__ Qb, bf16* __restrict__ Kb) {
  const int s = blockIdx.x;
  const int y = blockIdx.y;
  const int d = threadIdx.x;

  const bool isq = (y < 16);
  const int off = isq ? (y * HD + d) : (2048 + (y - 16) * HD + d);
  float x = (float)qkv[(size_t)s * QKV_N + off];

  float ss = x * x;
#pragma unroll
  for (int o = 32; o; o >>= 1) ss += __shfl_xor(ss, o);
  float inv = rsqrtf(ss * (1.f / 64.f) + 1e-6f);
  const float* wt = (d < 64) ? (isq ? qnw : knw) : (isq ? qnhw : knhw);
  float yn = x * inv * wt[d & 63];

  float pos, invf;
  int xorm;
  bool firsthalf;
  if (d < 64) {
    pos = (float)idx[s];
    int i = d & 31;
    invf = exp2f(-(float)i * 0.6228615177913804f);  // log2(1e6)/32
    xorm = 32;
    firsthalf = (d < 32);
  } else {
    int j = d - 64;
    int region = j >> 5;
    pos = (float)idx[(1 + region) * S_LEN + s];
    int i = j & 15;
    invf = exp2f(-(float)i * 0.8304820237218406f);  // log2(1e4)/16
    xorm = 16;
    firsthalf = ((j & 31) < 16);
  }
  float ang = pos * invf;
  float si, co;
  sincosf(ang, &si, &co);
  float partner = __shfl_xor(yn, xorm);
  float outv = firsthalf ? (yn * co - partner * si) : (yn * co + partner * si);

  if (isq)
    Qb[((size_t)y * S_LEN + s) * HD + d] = (bf16)(outv * 0.12751745f);  // D^-0.5*log2e
  else
    Kb[((size_t)(y - 16) * S_LEN + s) * HD + d] = (bf16)outv;
}

// ---------------- V transpose: qkvB[s][3072+kv*128+d] -> VT[kv][d][s] ----------------
__global__ __launch_bounds__(256)
void vtrans(const bf16* __restrict__ qkv, bf16* __restrict__ VT) {
  __shared__ bf16 T[64][72];
  const int tid = threadIdx.x;
  const int s0 = blockIdx.x * 64, d0 = blockIdx.y * 64, kv = blockIdx.z;
#pragma unroll
  for (int it = 0; it < 2; it++) {
    int r = (tid >> 3) + it * 32;
    int c = (tid & 7) * 8;
    bf16x8 v = *(const bf16x8*)(qkv + (size_t)(s0 + r) * QKV_N + 3072 + kv * HD + d0 + c);
    *(bf16x8*)(&T[r][c]) = v;
  }
  __syncthreads();
#pragma unroll
  for (int it = 0; it < 2; it++) {
    int r = (tid >> 3) + it * 32;
    int c = (tid & 7) * 8;
    bf16x8 o;
#pragma unroll
    for (int j = 0; j < 8; j++) o[j] = T[c + j][r];
    *(bf16x8*)(VT + ((size_t)kv * HD + d0 + r) * S_LEN + s0 + c) = o;
  }
}

// ---------------- Flash attention: 2 Q-bands (128 rows) per block ----------------
// 432 blocks x 256 thr. b: head h=b&15, cid=b>>4 in [0,27):
//   cid<7  : band G=cid (rows G*128..+127), single chunk, direct bf16 write.
//   7..20  : t=cid-7,  G=7+t/2,  chunk c=t&1  (2 chunks).
//   21..26 : t=cid-21, G=14+t/3, chunk c=t%3  (3 chunks).
// Chunk tiles [c*14, min(c*14+14, 2G+2)). Each wave owns rows {G*128+w*16,
// G*128+64+w*16} (two 64-row halves sharing the staged K/V tile -> 64 MFMA per
// barrier instead of 32). Half 0 skips tile 2G+1 (fully masked).
// K double-buffered LDS DMA, V LDS DMA drained with vmcnt(4), DPP softmax
// (base-2, Q pre-scaled), defer-max. Multi-chunk bands write f32 partials.
__global__ __launch_bounds__(256)
void attn_fused(const bf16* __restrict__ Qb, const bf16* __restrict__ Kb,
                const bf16* __restrict__ VT, bf16* __restrict__ attnO,
                char* __restrict__ Opart) {
  __shared__ bf16 Kbuf[2][8192];              // 16 KB x2
  __shared__ bf16 Vbuf[8192];                 // 16 KB
  __shared__ __align__(16) bf16 Ps[4][2][16][72];
  const int tid = threadIdx.x;
  const int w = tid >> 6, lane = tid & 63;
  const int quad = lane >> 4, l15 = lane & 15;
  const int b = blockIdx.x;
  const int h = b & 15;
  const int cid = b >> 4;
  int G, c, nc;
  if (cid < 7)       { G = cid;          c = 0;     nc = 1; }
  else if (cid < 21) { int t = cid - 7;  G = 7 + (t >> 1);  c = t & 1; nc = 2; }
  else               { int t = cid - 21; G = 14 + t / 3;    c = t % 3; nc = 3; }
  const int nT = 2 * G + 2;
  const int tBeg = c * 14;
  const int tEnd = (tBeg + 14 < nT) ? (tBeg + 14) : nT;
  const int tCap0 = 2 * G + 1;   // half 0 valid tiles: t < tCap0
  const int kv = h >> 1;
  const int qr0h[2] = {G * 128 + w * 16, G * 128 + 64 + w * 16};

  const bf16* Qg = Qb + (size_t)h * S_LEN * HD;
  const bf16* Kg = Kb + (size_t)kv * S_LEN * HD;
  const bf16* Vg = VT + (size_t)kv * HD * S_LEN;

  // per-lane DMA source bases (tile offset added later)
  const bf16* ksrc = Kg + (size_t)(w * 16 + l15) * HD + quad * 8;
  const bf16* vsrc = Vg + (size_t)(2 * w * 16 + l15) * S_LEN + quad * 8;

  // Q fragments (A-layout) for both halves, resident; Q pre-scaled
  bf16x8 aq[2][4];
#pragma unroll
  for (int bb = 0; bb < 2; bb++)
#pragma unroll
    for (int kc = 0; kc < 4; kc++)
      aq[bb][kc] = *(const bf16x8*)(Qg + (size_t)(qr0h[bb] + l15) * HD + kc * 32 + quad * 8);

  float m2[2][4], li[2][4];
  f32x4 Oacc[2][8];
#pragma unroll
  for (int bb = 0; bb < 2; bb++) {
#pragma unroll
    for (int r = 0; r < 4; r++) { m2[bb][r] = -1e30f; li[bb][r] = 0.f; }
#pragma unroll
    for (int dt = 0; dt < 8; dt++) Oacc[bb][dt] = (f32x4){0.f, 0.f, 0.f, 0.f};
  }

  // prologue: stage K tile tBeg into buf tBeg&1
#pragma unroll
  for (int kc = 0; kc < 4; kc++)
    async_load16(ksrc + (size_t)(tBeg << 6) * HD + kc * 32,
                 (char*)Kbuf[tBeg & 1] + (w * 4 + kc) * 1024);

  for (int tt = tBeg; tt < tEnd; ++tt) {
    const int t0 = tt << 6;
    const int cur = tt & 1;
    const bool more = (tt + 1 < tEnd);
    const bool do0 = (tt < tCap0);  // block-uniform
    __asm__ __volatile__("s_waitcnt vmcnt(0)" ::: "memory");  // own K DMA landed
    __syncthreads();                                          // all waves' DMA landed

    // issue V(tt) first (oldest 4), then K(tt+1) prefetch
#pragma unroll
    for (int e = 0; e < 2; e++)
#pragma unroll
      for (int half = 0; half < 2; half++)
        async_load16(vsrc + (size_t)e * 16 * S_LEN + t0 + half * 32,
                     (char*)Vbuf + (half * 8 + 2 * w + e) * 1024);
    if (more) {
#pragma unroll
      for (int kc = 0; kc < 4; kc++)
        async_load16(ksrc + (size_t)(t0 + 64) * HD + kc * 32,
                     (char*)Kbuf[cur ^ 1] + (w * 4 + kc) * 1024);
    }

    // ---- QK^T + softmax for each 64-row half ----
#pragma unroll
    for (int bb = 0; bb < 2; bb++) {
      if (bb == 0 && !do0) continue;
      const int qr0 = qr0h[bb];
      f32x4 sacc[4];
#pragma unroll
      for (int nt = 0; nt < 4; nt++) {
        sacc[nt] = (f32x4){0.f, 0.f, 0.f, 0.f};
#pragma unroll
        for (int kc = 0; kc < 4; kc++) {
          bf16x8 bk = *(const bf16x8*)((const char*)Kbuf[cur] + (nt * 4 + kc) * 1024 + lane * 16);
          sacc[nt] = __builtin_amdgcn_mfma_f32_16x16x32_bf16(aq[bb][kc], bk, sacc[nt], 0, 0, 0);
        }
      }
      const bool full = (t0 + 64 <= qr0);
      float mxv[4];
      bool need = false;
#pragma unroll
      for (int r = 0; r < 4; r++) {
        if (!full) {
          const int mrow = qr0 + quad * 4 + r;
          const int cb = t0 + l15;
          if (cb > mrow) sacc[0][r] = -1e30f;
          if (cb + 16 > mrow) sacc[1][r] = -1e30f;
          if (cb + 32 > mrow) sacc[2][r] = -1e30f;
          if (cb + 48 > mrow) sacc[3][r] = -1e30f;
        }
        mxv[r] = rowmax16(fmaxf(fmaxf(sacc[0][r], sacc[1][r]), fmaxf(sacc[2][r], sacc[3][r])));
        need = need || (mxv[r] > m2[bb][r] + 8.f);
      }
      if (__any(need ? 1 : 0)) {
#pragma unroll
        for (int r = 0; r < 4; r++) {
          float mnew = fmaxf(m2[bb][r], mxv[r]);
          float a = exp2f(m2[bb][r] - mnew);
          li[bb][r] *= a;
#pragma unroll
          for (int dt = 0; dt < 8; dt++) Oacc[bb][dt][r] *= a;
          m2[bb][r] = mnew;
        }
      }
#pragma unroll
      for (int r = 0; r < 4; r++) {
        float p0 = exp2f(sacc[0][r] - m2[bb][r]);
        float p1 = exp2f(sacc[1][r] - m2[bb][r]);
        float p2 = exp2f(sacc[2][r] - m2[bb][r]);
        float p3 = exp2f(sacc[3][r] - m2[bb][r]);
        li[bb][r] += rowsum16((p0 + p1) + (p2 + p3));
        Ps[w][bb][quad * 4 + r][l15] = (bf16)p0;
        Ps[w][bb][quad * 4 + r][16 + l15] = (bf16)p1;
        Ps[w][bb][quad * 4 + r][32 + l15] = (bf16)p2;
        Ps[w][bb][quad * 4 + r][48 + l15] = (bf16)p3;
      }
    }
    __asm__ __volatile__("s_waitcnt lgkmcnt(0)" ::: "memory");  // P RAW (wave-local)
    if (more)
      __asm__ __volatile__("s_waitcnt vmcnt(4)" ::: "memory");  // V landed (K prefetch stays)
    else
      __asm__ __volatile__("s_waitcnt vmcnt(0)" ::: "memory");

    // ---- PV from Vbuf (shared by both halves) ----
#pragma unroll
    for (int bb = 0; bb < 2; bb++) {
      if (bb == 0 && !do0) continue;
#pragma unroll
      for (int half = 0; half < 2; half++) {
        bf16x8 ap = *(const bf16x8*)(&Ps[w][bb][l15][half * 32 + quad * 8]);
#pragma unroll
        for (int dt = 0; dt < 8; dt++) {
          bf16x8 bv = *(const bf16x8*)((const char*)Vbuf + (half * 8 + dt) * 1024 + lane * 16);
          Oacc[bb][dt] = __builtin_amdgcn_mfma_f32_16x16x32_bf16(ap, bv, Oacc[bb][dt], 0, 0, 0);
        }
      }
    }
  }

  if (nc > 1) {
    // f32 partials: slot = (cid-7)*16 + h; rows 0..127 = bb*64 + w*16 + quad*4 + r
    char* slot = Opart + (size_t)((cid - 7) * 16 + h) * PSLOT;
    float* Op = (float*)slot;
    float* mlp = (float*)(slot + 65536);
#pragma unroll
    for (int bb = 0; bb < 2; bb++) {
#pragma unroll
      for (int r = 0; r < 4; r++) {
        const int row = bb * 64 + w * 16 + quad * 4 + r;
#pragma unroll
        for (int dt = 0; dt < 8; dt++)
          Op[row * 128 + dt * 16 + l15] = Oacc[bb][dt][r];
        if (l15 == 0) {
          mlp[row * 2 + 0] = m2[bb][r];
          mlp[row * 2 + 1] = li[bb][r];
        }
      }
    }
  } else {
#pragma unroll
    for (int bb = 0; bb < 2; bb++) {
#pragma unroll
      for (int r = 0; r < 4; r++) {
        float invl = 1.f / li[bb][r];
        int srow = qr0h[bb] + quad * 4 + r;
#pragma unroll
        for (int dt = 0; dt < 8; dt++)
          attnO[(size_t)srow * HIDDEN + h * HD + dt * 16 + l15] = (bf16)(Oacc[bb][dt][r] * invl);
      }
    }
  }
}

// ---------------- merge 2-3 chunk partials (bands G in [7,16)) ----------------
__global__ __launch_bounds__(256)
void attn_merge(const char* __restrict__ Opart, bf16* __restrict__ attnO) {
  const int h = blockIdx.x & 15;
  const int idx = blockIdx.x >> 4;   // 0..8
  int G, nc, cid0;
  if (idx < 7) { G = 7 + idx;        nc = 2; cid0 = 7 + idx * 2; }
  else         { G = 14 + (idx - 7); nc = 3; cid0 = 21 + (idx - 7) * 3; }
  const char* s0 = Opart + (size_t)((cid0 - 7) * 16 + h) * PSLOT;
  const char* s1 = s0 + (size_t)16 * PSLOT;
  const char* s2 = s0 + (size_t)32 * PSLOT;
  const float* O0 = (const float*)s0;
  const float* O1 = (const float*)s1;
  const float* O2 = (const float*)s2;
  const float* ML0 = (const float*)(s0 + 65536);
  const float* ML1 = (const float*)(s1 + 65536);
  const float* ML2 = (const float*)(s2 + 65536);
  const int t = threadIdx.x;
#pragma unroll
  for (int it = 0; it < 16; ++it) {
    int e = it * 256 + t;
    int row = e >> 5, d = (e & 31) * 4;
    float m0 = ML0[row * 2], l0 = ML0[row * 2 + 1];
    float m1 = ML1[row * 2], l1 = ML1[row * 2 + 1];
    float m2v = -1e30f, l2v = 0.f;
    if (nc == 3) { m2v = ML2[row * 2]; l2v = ML2[row * 2 + 1]; }
    float m = fmaxf(fmaxf(m0, m1), m2v);
    float a0 = exp2f(m0 - m), a1 = exp2f(m1 - m), a2 = exp2f(m2v - m);
    float inv = 1.f / (a0 * l0 + a1 * l1 + a2 * l2v);
    f32x4 x0 = *(const f32x4*)(O0 + row * 128 + d);
    f32x4 x1 = *(const f32x4*)(O1 + row * 128 + d);
    f32x4 x2 = (f32x4){0.f, 0.f, 0.f, 0.f};
    if (nc == 3) x2 = *(const f32x4*)(O2 + row * 128 + d);
    int srow = G * 128 + row;
    bf16x4 o;
#pragma unroll
    for (int j = 0; j < 4; j++)
      o[j] = (bf16)((a0 * x0[j] + a1 * x1[j] + a2 * x2[j]) * inv);
    *(bf16x4*)(attnO + (size_t)srow * HIDDEN + h * HD + d) = o;
  }
}

extern "C" void kernel_launch(void* const* d_in, const int* in_sizes, int n_in,
                              void* d_out, int out_size, void* d_ws, size_t ws_size,
                              hipStream_t stream) {
  const float* hidden = (const float*)d_in[0];
  const int* idx = (const int*)d_in[1];
  const float* qkv_w = (const float*)d_in[3];
  const float* qkv_b = (const float*)d_in[4];
  const float* o_w = (const float*)d_in[5];
  const float* o_b = (const float*)d_in[6];
  const float* qnw = (const float*)d_in[7];
  const float* knw = (const float*)d_in[8];
  const float* qnhw = (const float*)d_in[9];
  const float* knhw = (const float*)d_in[10];

  char* ws = (char*)d_ws;
  // layout (MiB): [0,8) hB/owB | [8,24) qwB | [24,40) qkvB | [40,48) Qb
  //               [48,52) Kb | [52,56) VT
  // after GEMM1+vtrans: Opart at [8, 28.3) (320 slots * 65 KB), attn at [32,40)
  bf16* hB    = (bf16*)(ws);
  bf16* qwB   = (bf16*)(ws + (8u << 20));
  bf16* qkvB  = (bf16*)(ws + (24u << 20));
  bf16* Qb    = (bf16*)(ws + (40u << 20));
  bf16* Kb    = (bf16*)(ws + (48u << 20));
  bf16* VT    = (bf16*)(ws + (52u << 20));
  bf16* owB   = hB;                          // reuse after GEMM1
  char* Opart = ws + (8u << 20);             // 320 * 66560 B = 20.3 MiB
  bf16* attn  = (bf16*)(ws + (32u << 20));   // reuse qkvB upper half after vtrans

  cvt_pair<<<12288, 256, 0, stream>>>(hidden, hB, HIDDEN * S_LEN,
                                      qkv_w, qwB, QKV_N * HIDDEN);

  gemm_bt<1><<<dim3(QKV_N / 128, S_LEN / 128), 256, 0, stream>>>(
      hB, qwB, qkv_b, qkvB, S_LEN, QKV_N, HIDDEN);

  cvt_f32_bf16<<<HIDDEN * HIDDEN / 1024, 256, 0, stream>>>(o_w, owB, HIDDEN * HIDDEN);

  normrope<<<dim3(S_LEN, 24), 128, 0, stream>>>(qkvB, idx, qnw, knw, qnhw, knhw, Qb, Kb);
  vtrans<<<dim3(S_LEN / 64, HD / 64, NKV), 256, 0, stream>>>(qkvB, VT);

  attn_fused<<<432, 256, 0, stream>>>(Qb, Kb, VT, attn, Opart);
  attn_merge<<<144, 256, 0, stream>>>(Opart, attn);

  gemm_bt<0><<<dim3(HIDDEN / 128, S_LEN / 128), 256, 0, stream>>>(
      attn, owB, o_b, (float*)d_out, S_LEN, HIDDEN, HIDDEN);
}

// Round 7
// 300.492 us; speedup vs baseline: 1.0549x; 1.0549x over previous
//
#include <hip/hip_runtime.h>

typedef __bf16 bf16;
typedef __bf16 bf16x4 __attribute__((ext_vector_type(4)));
typedef __bf16 bf16x8 __attribute__((ext_vector_type(8)));
typedef float f32x4 __attribute__((ext_vector_type(4)));

#define S_LEN 2048
#define HIDDEN 2048
#define NH 16
#define NKV 8
#define HD 128
#define QKV_N 4096

// partial slot: 128x128 f32 O (65536 B) + 128x{m,l} f32 (1024 B)
#define PSLOT 66560

__device__ __forceinline__ void async_load16(const void* g, void* l) {
  __builtin_amdgcn_global_load_lds((const __attribute__((address_space(1))) unsigned int*)g,
                                   (__attribute__((address_space(3))) unsigned int*)l,
                                   16, 0, 0);
}

// ---- DPP 16-lane (row) reductions: row == our quad domain (l15) ----
template <int C>
__device__ __forceinline__ float dpp_f(float x) {
  return __builtin_bit_cast(float, __builtin_amdgcn_mov_dpp(
      __builtin_bit_cast(int, x), C, 0xF, 0xF, true));
}
__device__ __forceinline__ float rowmax16(float x) {
  x = fmaxf(x, dpp_f<0x128>(x));  // row_ror:8
  x = fmaxf(x, dpp_f<0x124>(x));  // row_ror:4
  x = fmaxf(x, dpp_f<0x122>(x));  // row_ror:2
  x = fmaxf(x, dpp_f<0x121>(x));  // row_ror:1
  return x;
}
__device__ __forceinline__ float rowsum16(float x) {
  x += dpp_f<0x128>(x);
  x += dpp_f<0x124>(x);
  x += dpp_f<0x122>(x);
  x += dpp_f<0x121>(x);
  return x;
}

// ---------------- fp32 -> bf16 convert (single) ----------------
__global__ __launch_bounds__(256)
void cvt_f32_bf16(const float* __restrict__ src, bf16* __restrict__ dst, int n) {
  int i = (blockIdx.x * 256 + threadIdx.x) * 4;
  if (i < n) {
    float4 v = *(const float4*)(src + i);
    bf16x4 o = {(bf16)v.x, (bf16)v.y, (bf16)v.z, (bf16)v.w};
    *(bf16x4*)(dst + i) = o;
  }
}

// ---------------- fp32 -> bf16 convert (two arrays fused) ----------------
__global__ __launch_bounds__(256)
void cvt_pair(const float* __restrict__ s1, bf16* __restrict__ d1, int n1,
              const float* __restrict__ s2, bf16* __restrict__ d2, int n2) {
  int i = (blockIdx.x * 256 + threadIdx.x) * 4;
  const float* s;
  bf16* d;
  int j;
  if (i < n1) { s = s1; d = d1; j = i; }
  else        { s = s2; d = d2; j = i - n1; if (j >= n2) return; }
  float4 v = *(const float4*)(s + j);
  bf16x4 o = {(bf16)v.x, (bf16)v.y, (bf16)v.z, (bf16)v.w};
  *(bf16x4*)(d + j) = o;
}

// ---------------- GEMM 128x128, BK=64: C[M,N] = A[M,K] * B[N,K]^T + bias -------
// Double-buffered LDS 2-phase, stage(k+1) before compute(k), one vmcnt(0)+barrier
// per 64-wide K-step (32 MFMA per drain). LDS 64 KB -> 2 blocks/CU, which matches
// the grid (512 / 256 blocks = 2 / 1 per CU), so no occupancy loss vs BK=32.
// Fragment-major 1KB chunks (16 rows x 32 cols), lane-linear, conflict-free.
template <int WRITE_BF16>
__global__ __launch_bounds__(256)
void gemm_bt(const bf16* __restrict__ A, const bf16* __restrict__ B,
             const float* __restrict__ bias, void* __restrict__ Cout,
             int M, int N, int K) {
  __shared__ bf16 As[2][128 * 64];   // 32 KB
  __shared__ bf16 Bs[2][128 * 64];   // 32 KB
  const int tid = threadIdx.x;
  const int w = tid >> 6, lane = tid & 63;
  const int quad = lane >> 4, l15 = lane & 15;
  const int wm = w >> 1, wn = w & 1;
  const int m0 = blockIdx.y * 128, n0 = blockIdx.x * 128;

  f32x4 acc[4][4];
#pragma unroll
  for (int i = 0; i < 4; i++)
#pragma unroll
    for (int j = 0; j < 4; j++) acc[i][j] = (f32x4){0.f, 0.f, 0.f, 0.f};

  const int crow = lane >> 2;        // 0..15
  const int ccol = (lane & 3) * 8;   // 0,8,16,24

  // chunk c = w*4+q: rb = c>>1 (row block 0..7), kh = c&1 (k half 0..1)
  // prologue: stage k0=0 into buf 0
#pragma unroll
  for (int q = 0; q < 4; q++) {
    int c = w * 4 + q, rb = c >> 1, kh = c & 1;
    async_load16(A + (size_t)(m0 + rb * 16 + crow) * K + kh * 32 + ccol,
                 (char*)As[0] + c * 1024);
    async_load16(B + (size_t)(n0 + rb * 16 + crow) * K + kh * 32 + ccol,
                 (char*)Bs[0] + c * 1024);
  }

  int cur = 0;
  for (int k0 = 0; k0 < K; k0 += 64) {
    __asm__ __volatile__("s_waitcnt vmcnt(0)" ::: "memory");  // buf[cur] DMA landed
    __syncthreads();
    if (k0 + 64 < K) {
#pragma unroll
      for (int q = 0; q < 4; q++) {
        int c = w * 4 + q, rb = c >> 1, kh = c & 1;
        async_load16(A + (size_t)(m0 + rb * 16 + crow) * K + k0 + 64 + kh * 32 + ccol,
                     (char*)As[cur ^ 1] + c * 1024);
        async_load16(B + (size_t)(n0 + rb * 16 + crow) * K + k0 + 64 + kh * 32 + ccol,
                     (char*)Bs[cur ^ 1] + c * 1024);
      }
    }
    bf16x8 af[4][2], bfr[4][2];
#pragma unroll
    for (int i = 0; i < 4; i++)
#pragma unroll
      for (int kk = 0; kk < 2; kk++)
        af[i][kk] = *(const bf16x8*)((const char*)As[cur] +
                                     ((wm * 4 + i) * 2 + kk) * 1024 + l15 * 64 + quad * 16);
#pragma unroll
    for (int j = 0; j < 4; j++)
#pragma unroll
      for (int kk = 0; kk < 2; kk++)
        bfr[j][kk] = *(const bf16x8*)((const char*)Bs[cur] +
                                      ((wn * 4 + j) * 2 + kk) * 1024 + l15 * 64 + quad * 16);
#pragma unroll
    for (int kk = 0; kk < 2; kk++)
#pragma unroll
      for (int i = 0; i < 4; i++)
#pragma unroll
        for (int j = 0; j < 4; j++)
          acc[i][j] = __builtin_amdgcn_mfma_f32_16x16x32_bf16(af[i][kk], bfr[j][kk],
                                                              acc[i][j], 0, 0, 0);
    cur ^= 1;
  }

#pragma unroll
  for (int i = 0; i < 4; i++) {
#pragma unroll
    for (int j = 0; j < 4; j++) {
      int col = n0 + wn * 64 + j * 16 + l15;
      float bv = bias[col];
#pragma unroll
      for (int r = 0; r < 4; r++) {
        int row = m0 + wm * 64 + i * 16 + quad * 4 + r;
        float v = acc[i][j][r] + bv;
        if (WRITE_BF16)
          ((bf16*)Cout)[(size_t)row * N + col] = (bf16)v;
        else
          ((float*)Cout)[(size_t)row * N + col] = v;
      }
    }
  }
}

// ---------------- RMS norm + RoPE -> Q/K head-major bf16 ----------------
// Q is pre-scaled by D^-0.5 * log2(e) so attn softmax uses raw QK^T logits in base-2.
// 8 s-positions per block (amortizes per-block overhead; per-element math identical).
__global__ __launch_bounds__(128)
void normrope(const bf16* __restrict__ qkv, const int* __restrict__ idx,
              const float* __restrict__ qnw, const float* __restrict__ knw,
              const float* __restrict__ qnhw, const float* __restrict__ knhw,
              bf16* __restrict__ Qb, bf16* __restrict__ Kb) {
  const int y = blockIdx.y;
  const int d = threadIdx.x;

  const bool isq = (y < 16);
  const int off = isq ? (y * HD + d) : (2048 + (y - 16) * HD + d);
  const float* wt = (d < 64) ? (isq ? qnw : knw) : (isq ? qnhw : knhw);
  const float wv = wt[d & 63];

  float invf;
  int xorm, posrow;
  bool firsthalf;
  if (d < 64) {
    int i = d & 31;
    invf = exp2f(-(float)i * 0.6228615177913804f);  // log2(1e6)/32
    xorm = 32;
    firsthalf = (d < 32);
    posrow = 0;
  } else {
    int j = d - 64;
    int region = j >> 5;
    int i = j & 15;
    invf = exp2f(-(float)i * 0.8304820237218406f);  // log2(1e4)/16
    xorm = 16;
    firsthalf = ((j & 31) < 16);
    posrow = 1 + region;
  }

  bf16* outp = isq ? (Qb + ((size_t)y * S_LEN) * HD + d)
                   : (Kb + ((size_t)(y - 16) * S_LEN) * HD + d);
  const float oscale = isq ? 0.12751745f : 1.0f;  // D^-0.5*log2e folded into Q

#pragma unroll
  for (int si = 0; si < 8; si++) {
    const int s = blockIdx.x * 8 + si;
    float x = (float)qkv[(size_t)s * QKV_N + off];

    float ss = x * x;
#pragma unroll
    for (int o = 32; o; o >>= 1) ss += __shfl_xor(ss, o);
    float inv = rsqrtf(ss * (1.f / 64.f) + 1e-6f);
    float yn = x * inv * wv;

    float pos = (float)idx[posrow * S_LEN + s];
    float ang = pos * invf;
    float si_, co;
    sincosf(ang, &si_, &co);
    float partner = __shfl_xor(yn, xorm);
    float outv = firsthalf ? (yn * co - partner * si_) : (yn * co + partner * si_);
    outp[(size_t)s * HD] = (bf16)(outv * oscale);
  }
}

// ---------------- V transpose: qkvB[s][3072+kv*128+d] -> VT[kv][d][s] ----------------
__global__ __launch_bounds__(256)
void vtrans(const bf16* __restrict__ qkv, bf16* __restrict__ VT) {
  __shared__ bf16 T[64][72];
  const int tid = threadIdx.x;
  const int s0 = blockIdx.x * 64, d0 = blockIdx.y * 64, kv = blockIdx.z;
#pragma unroll
  for (int it = 0; it < 2; it++) {
    int r = (tid >> 3) + it * 32;
    int c = (tid & 7) * 8;
    bf16x8 v = *(const bf16x8*)(qkv + (size_t)(s0 + r) * QKV_N + 3072 + kv * HD + d0 + c);
    *(bf16x8*)(&T[r][c]) = v;
  }
  __syncthreads();
#pragma unroll
  for (int it = 0; it < 2; it++) {
    int r = (tid >> 3) + it * 32;
    int c = (tid & 7) * 8;
    bf16x8 o;
#pragma unroll
    for (int j = 0; j < 8; j++) o[j] = T[c + j][r];
    *(bf16x8*)(VT + ((size_t)kv * HD + d0 + r) * S_LEN + s0 + c) = o;
  }
}

// ---------------- Flash attention: 2 Q-bands (128 rows) per block ----------------
// 432 blocks x 256 thr. b: head h=b&15, cid=b>>4 in [0,27):
//   cid<7  : band G=cid (rows G*128..+127), single chunk, direct bf16 write.
//   7..20  : t=cid-7,  G=7+t/2,  chunk c=t&1  (2 chunks).
//   21..26 : t=cid-21, G=14+t/3, chunk c=t%3  (3 chunks).
// Chunk tiles [c*14, min(c*14+14, 2G+2)). Each wave owns rows {G*128+w*16,
// G*128+64+w*16} (two 64-row halves sharing the staged K/V tile -> 64 MFMA per
// barrier instead of 32). Half 0 skips tile 2G+1 (fully masked).
// K double-buffered LDS DMA, V LDS DMA drained with vmcnt(4), DPP softmax
// (base-2, Q pre-scaled), defer-max. Multi-chunk bands write f32 partials.
__global__ __launch_bounds__(256)
void attn_fused(const bf16* __restrict__ Qb, const bf16* __restrict__ Kb,
                const bf16* __restrict__ VT, bf16* __restrict__ attnO,
                char* __restrict__ Opart) {
  __shared__ bf16 Kbuf[2][8192];              // 16 KB x2
  __shared__ bf16 Vbuf[8192];                 // 16 KB
  __shared__ __align__(16) bf16 Ps[4][2][16][72];
  const int tid = threadIdx.x;
  const int w = tid >> 6, lane = tid & 63;
  const int quad = lane >> 4, l15 = lane & 15;
  const int b = blockIdx.x;
  const int h = b & 15;
  const int cid = b >> 4;
  int G, c, nc;
  if (cid < 7)       { G = cid;          c = 0;     nc = 1; }
  else if (cid < 21) { int t = cid - 7;  G = 7 + (t >> 1);  c = t & 1; nc = 2; }
  else               { int t = cid - 21; G = 14 + t / 3;    c = t % 3; nc = 3; }
  const int nT = 2 * G + 2;
  const int tBeg = c * 14;
  const int tEnd = (tBeg + 14 < nT) ? (tBeg + 14) : nT;
  const int tCap0 = 2 * G + 1;   // half 0 valid tiles: t < tCap0
  const int kv = h >> 1;
  const int qr0h[2] = {G * 128 + w * 16, G * 128 + 64 + w * 16};

  const bf16* Qg = Qb + (size_t)h * S_LEN * HD;
  const bf16* Kg = Kb + (size_t)kv * S_LEN * HD;
  const bf16* Vg = VT + (size_t)kv * HD * S_LEN;

  // per-lane DMA source bases (tile offset added later)
  const bf16* ksrc = Kg + (size_t)(w * 16 + l15) * HD + quad * 8;
  const bf16* vsrc = Vg + (size_t)(2 * w * 16 + l15) * S_LEN + quad * 8;

  // Q fragments (A-layout) for both halves, resident; Q pre-scaled
  bf16x8 aq[2][4];
#pragma unroll
  for (int bb = 0; bb < 2; bb++)
#pragma unroll
    for (int kc = 0; kc < 4; kc++)
      aq[bb][kc] = *(const bf16x8*)(Qg + (size_t)(qr0h[bb] + l15) * HD + kc * 32 + quad * 8);

  float m2[2][4], li[2][4];
  f32x4 Oacc[2][8];
#pragma unroll
  for (int bb = 0; bb < 2; bb++) {
#pragma unroll
    for (int r = 0; r < 4; r++) { m2[bb][r] = -1e30f; li[bb][r] = 0.f; }
#pragma unroll
    for (int dt = 0; dt < 8; dt++) Oacc[bb][dt] = (f32x4){0.f, 0.f, 0.f, 0.f};
  }

  // prologue: stage K tile tBeg into buf tBeg&1
#pragma unroll
  for (int kc = 0; kc < 4; kc++)
    async_load16(ksrc + (size_t)(tBeg << 6) * HD + kc * 32,
                 (char*)Kbuf[tBeg & 1] + (w * 4 + kc) * 1024);

  for (int tt = tBeg; tt < tEnd; ++tt) {
    const int t0 = tt << 6;
    const int cur = tt & 1;
    const bool more = (tt + 1 < tEnd);
    const bool do0 = (tt < tCap0);  // block-uniform
    __asm__ __volatile__("s_waitcnt vmcnt(0)" ::: "memory");  // own K DMA landed
    __syncthreads();                                          // all waves' DMA landed

    // issue V(tt) first (oldest 4), then K(tt+1) prefetch
#pragma unroll
    for (int e = 0; e < 2; e++)
#pragma unroll
      for (int half = 0; half < 2; half++)
        async_load16(vsrc + (size_t)e * 16 * S_LEN + t0 + half * 32,
                     (char*)Vbuf + (half * 8 + 2 * w + e) * 1024);
    if (more) {
#pragma unroll
      for (int kc = 0; kc < 4; kc++)
        async_load16(ksrc + (size_t)(t0 + 64) * HD + kc * 32,
                     (char*)Kbuf[cur ^ 1] + (w * 4 + kc) * 1024);
    }

    // ---- QK^T + softmax for each 64-row half ----
#pragma unroll
    for (int bb = 0; bb < 2; bb++) {
      if (bb == 0 && !do0) continue;
      const int qr0 = qr0h[bb];
      f32x4 sacc[4];
#pragma unroll
      for (int nt = 0; nt < 4; nt++) {
        sacc[nt] = (f32x4){0.f, 0.f, 0.f, 0.f};
#pragma unroll
        for (int kc = 0; kc < 4; kc++) {
          bf16x8 bk = *(const bf16x8*)((const char*)Kbuf[cur] + (nt * 4 + kc) * 1024 + lane * 16);
          sacc[nt] = __builtin_amdgcn_mfma_f32_16x16x32_bf16(aq[bb][kc], bk, sacc[nt], 0, 0, 0);
        }
      }
      const bool full = (t0 + 64 <= qr0);
      float mxv[4];
      bool need = false;
#pragma unroll
      for (int r = 0; r < 4; r++) {
        if (!full) {
          const int mrow = qr0 + quad * 4 + r;
          const int cb = t0 + l15;
          if (cb > mrow) sacc[0][r] = -1e30f;
          if (cb + 16 > mrow) sacc[1][r] = -1e30f;
          if (cb + 32 > mrow) sacc[2][r] = -1e30f;
          if (cb + 48 > mrow) sacc[3][r] = -1e30f;
        }
        mxv[r] = rowmax16(fmaxf(fmaxf(sacc[0][r], sacc[1][r]), fmaxf(sacc[2][r], sacc[3][r])));
        need = need || (mxv[r] > m2[bb][r] + 8.f);
      }
      if (__any(need ? 1 : 0)) {
#pragma unroll
        for (int r = 0; r < 4; r++) {
          float mnew = fmaxf(m2[bb][r], mxv[r]);
          float a = exp2f(m2[bb][r] - mnew);
          li[bb][r] *= a;
#pragma unroll
          for (int dt = 0; dt < 8; dt++) Oacc[bb][dt][r] *= a;
          m2[bb][r] = mnew;
        }
      }
#pragma unroll
      for (int r = 0; r < 4; r++) {
        float p0 = exp2f(sacc[0][r] - m2[bb][r]);
        float p1 = exp2f(sacc[1][r] - m2[bb][r]);
        float p2 = exp2f(sacc[2][r] - m2[bb][r]);
        float p3 = exp2f(sacc[3][r] - m2[bb][r]);
        li[bb][r] += rowsum16((p0 + p1) + (p2 + p3));
        Ps[w][bb][quad * 4 + r][l15] = (bf16)p0;
        Ps[w][bb][quad * 4 + r][16 + l15] = (bf16)p1;
        Ps[w][bb][quad * 4 + r][32 + l15] = (bf16)p2;
        Ps[w][bb][quad * 4 + r][48 + l15] = (bf16)p3;
      }
    }
    __asm__ __volatile__("s_waitcnt lgkmcnt(0)" ::: "memory");  // P RAW (wave-local)
    if (more)
      __asm__ __volatile__("s_waitcnt vmcnt(4)" ::: "memory");  // V landed (K prefetch stays)
    else
      __asm__ __volatile__("s_waitcnt vmcnt(0)" ::: "memory");

    // ---- PV from Vbuf (shared by both halves) ----
#pragma unroll
    for (int bb = 0; bb < 2; bb++) {
      if (bb == 0 && !do0) continue;
#pragma unroll
      for (int half = 0; half < 2; half++) {
        bf16x8 ap = *(const bf16x8*)(&Ps[w][bb][l15][half * 32 + quad * 8]);
#pragma unroll
        for (int dt = 0; dt < 8; dt++) {
          bf16x8 bv = *(const bf16x8*)((const char*)Vbuf + (half * 8 + dt) * 1024 + lane * 16);
          Oacc[bb][dt] = __builtin_amdgcn_mfma_f32_16x16x32_bf16(ap, bv, Oacc[bb][dt], 0, 0, 0);
        }
      }
    }
  }

  if (nc > 1) {
    // f32 partials: slot = (cid-7)*16 + h; rows 0..127 = bb*64 + w*16 + quad*4 + r
    char* slot = Opart + (size_t)((cid - 7) * 16 + h) * PSLOT;
    float* Op = (float*)slot;
    float* mlp = (float*)(slot + 65536);
#pragma unroll
    for (int bb = 0; bb < 2; bb++) {
#pragma unroll
      for (int r = 0; r < 4; r++) {
        const int row = bb * 64 + w * 16 + quad * 4 + r;
#pragma unroll
        for (int dt = 0; dt < 8; dt++)
          Op[row * 128 + dt * 16 + l15] = Oacc[bb][dt][r];
        if (l15 == 0) {
          mlp[row * 2 + 0] = m2[bb][r];
          mlp[row * 2 + 1] = li[bb][r];
        }
      }
    }
  } else {
#pragma unroll
    for (int bb = 0; bb < 2; bb++) {
#pragma unroll
      for (int r = 0; r < 4; r++) {
        float invl = 1.f / li[bb][r];
        int srow = qr0h[bb] + quad * 4 + r;
#pragma unroll
        for (int dt = 0; dt < 8; dt++)
          attnO[(size_t)srow * HIDDEN + h * HD + dt * 16 + l15] = (bf16)(Oacc[bb][dt][r] * invl);
      }
    }
  }
}

// ---------------- merge 2-3 chunk partials (bands G in [7,16)) ----------------
__global__ __launch_bounds__(256)
void attn_merge(const char* __restrict__ Opart, bf16* __restrict__ attnO) {
  const int h = blockIdx.x & 15;
  const int idx = blockIdx.x >> 4;   // 0..8
  int G, nc, cid0;
  if (idx < 7) { G = 7 + idx;        nc = 2; cid0 = 7 + idx * 2; }
  else         { G = 14 + (idx - 7); nc = 3; cid0 = 21 + (idx - 7) * 3; }
  const char* s0 = Opart + (size_t)((cid0 - 7) * 16 + h) * PSLOT;
  const char* s1 = s0 + (size_t)16 * PSLOT;
  const char* s2 = s0 + (size_t)32 * PSLOT;
  const float* O0 = (const float*)s0;
  const float* O1 = (const float*)s1;
  const float* O2 = (const float*)s2;
  const float* ML0 = (const float*)(s0 + 65536);
  const float* ML1 = (const float*)(s1 + 65536);
  const float* ML2 = (const float*)(s2 + 65536);
  const int t = threadIdx.x;
#pragma unroll
  for (int it = 0; it < 16; ++it) {
    int e = it * 256 + t;
    int row = e >> 5, d = (e & 31) * 4;
    float m0 = ML0[row * 2], l0 = ML0[row * 2 + 1];
    float m1 = ML1[row * 2], l1 = ML1[row * 2 + 1];
    float m2v = -1e30f, l2v = 0.f;
    if (nc == 3) { m2v = ML2[row * 2]; l2v = ML2[row * 2 + 1]; }
    float m = fmaxf(fmaxf(m0, m1), m2v);
    float a0 = exp2f(m0 - m), a1 = exp2f(m1 - m), a2 = exp2f(m2v - m);
    float inv = 1.f / (a0 * l0 + a1 * l1 + a2 * l2v);
    f32x4 x0 = *(const f32x4*)(O0 + row * 128 + d);
    f32x4 x1 = *(const f32x4*)(O1 + row * 128 + d);
    f32x4 x2 = (f32x4){0.f, 0.f, 0.f, 0.f};
    if (nc == 3) x2 = *(const f32x4*)(O2 + row * 128 + d);
    int srow = G * 128 + row;
    bf16x4 o;
#pragma unroll
    for (int j = 0; j < 4; j++)
      o[j] = (bf16)((a0 * x0[j] + a1 * x1[j] + a2 * x2[j]) * inv);
    *(bf16x4*)(attnO + (size_t)srow * HIDDEN + h * HD + d) = o;
  }
}

extern "C" void kernel_launch(void* const* d_in, const int* in_sizes, int n_in,
                              void* d_out, int out_size, void* d_ws, size_t ws_size,
                              hipStream_t stream) {
  const float* hidden = (const float*)d_in[0];
  const int* idx = (const int*)d_in[1];
  const float* qkv_w = (const float*)d_in[3];
  const float* qkv_b = (const float*)d_in[4];
  const float* o_w = (const float*)d_in[5];
  const float* o_b = (const float*)d_in[6];
  const float* qnw = (const float*)d_in[7];
  const float* knw = (const float*)d_in[8];
  const float* qnhw = (const float*)d_in[9];
  const float* knhw = (const float*)d_in[10];

  char* ws = (char*)d_ws;
  // layout (MiB): [0,8) hB/owB | [8,24) qwB | [24,40) qkvB | [40,48) Qb
  //               [48,52) Kb | [52,56) VT
  // after GEMM1+vtrans: Opart at [8, 28.3) (320 slots * 65 KB), attn at [32,40)
  bf16* hB    = (bf16*)(ws);
  bf16* qwB   = (bf16*)(ws + (8u << 20));
  bf16* qkvB  = (bf16*)(ws + (24u << 20));
  bf16* Qb    = (bf16*)(ws + (40u << 20));
  bf16* Kb    = (bf16*)(ws + (48u << 20));
  bf16* VT    = (bf16*)(ws + (52u << 20));
  bf16* owB   = hB;                          // reuse after GEMM1
  char* Opart = ws + (8u << 20);             // 320 * 66560 B = 20.3 MiB
  bf16* attn  = (bf16*)(ws + (32u << 20));   // reuse qkvB upper half after vtrans

  cvt_pair<<<12288, 256, 0, stream>>>(hidden, hB, HIDDEN * S_LEN,
                                      qkv_w, qwB, QKV_N * HIDDEN);

  gemm_bt<1><<<dim3(QKV_N / 128, S_LEN / 128), 256, 0, stream>>>(
      hB, qwB, qkv_b, qkvB, S_LEN, QKV_N, HIDDEN);

  cvt_f32_bf16<<<HIDDEN * HIDDEN / 1024, 256, 0, stream>>>(o_w, owB, HIDDEN * HIDDEN);

  normrope<<<dim3(S_LEN / 8, 24), 128, 0, stream>>>(qkvB, idx, qnw, knw, qnhw, knhw, Qb, Kb);
  vtrans<<<dim3(S_LEN / 64, HD / 64, NKV), 256, 0, stream>>>(qkvB, VT);

  attn_fused<<<432, 256, 0, stream>>>(Qb, Kb, VT, attn, Opart);
  attn_merge<<<144, 256, 0, stream>>>(Opart, attn);

  gemm_bt<0><<<dim3(HIDDEN / 128, S_LEN / 128), 256, 0, stream>>>(
      attn, owB, o_b, (float*)d_out, S_LEN, HIDDEN, HIDDEN);
}